// Round 8
// baseline (648.216 us; speedup 1.0000x reference)
//
#include <hip/hip_runtime.h>
#include <hip/hip_bf16.h>
#include <math.h>
#include <stdint.h>

typedef __attribute__((ext_vector_type(8))) short bf16x8_t;
typedef __attribute__((ext_vector_type(4))) float f32x4_t;

#define LOG2E 1.4426950408889634f
#define GLB(p) ((const __attribute__((address_space(1))) void*)(p))
#define LDS(p) ((__attribute__((address_space(3))) void*)(p))

__device__ __forceinline__ unsigned short f2bf(float f) {
    union { float f; unsigned int u; } v; v.f = f;
    unsigned int r = v.u + 0x7FFFu + ((v.u >> 16) & 1u);
    return (unsigned short)(r >> 16);
}

__device__ __forceinline__ float bf2f(unsigned short us) {
    union { unsigned int u; float f; } c; c.u = (unsigned int)us << 16; return c.f;
}

__device__ __forceinline__ unsigned int pack2bf(float a, float b) {
#if __has_builtin(__builtin_amdgcn_cvt_pk_bf16_f32)
    auto r = __builtin_amdgcn_cvt_pk_bf16_f32(a, b);
    unsigned int u;
    __builtin_memcpy(&u, &r, 4);
    return u;
#else
    return (unsigned int)f2bf(a) | ((unsigned int)f2bf(b) << 16);
#endif
}

// ---------------- fused cast fp32 -> bf16 for x, enc + mask4 prep ----------------
// mask4[b][t][l16][nt] = maskp[b*2048 + t*64 + nt*16 + l16] ? -1e10 : 0  (8192 floats)
__global__ void cast2_bf16_k(const float* __restrict__ inA, unsigned short* __restrict__ outA,
                             const float* __restrict__ inB, unsigned short* __restrict__ outB,
                             int n4, const int* __restrict__ maskp, float* __restrict__ mask4) {
    if (blockIdx.y == 2) {
        int i = blockIdx.x * blockDim.x + threadIdx.x;
        if (i < 8192) {
            int nt = i & 3, l16 = (i >> 2) & 15, t = (i >> 6) & 31, b = (i >> 11) & 1;
            mask4[i] = maskp[b * 2048 + t * 64 + nt * 16 + l16] ? -1e10f : 0.0f;
        }
        return;
    }
    const float* in = blockIdx.y ? inB : inA;
    unsigned short* out = blockIdx.y ? outB : outA;
    int i = blockIdx.x * blockDim.x + threadIdx.x;
    if (i < n4) {
        float4 v = ((const float4*)in)[i];
        ushort4 o;
        o.x = f2bf(v.x); o.y = f2bf(v.y); o.z = f2bf(v.z); o.w = f2bf(v.w);
        ((ushort4*)out)[i] = o;
    }
}

// ---------------- fused weight transpose+cast: all 8 weights in one dispatch ----------------
__global__ void transpose_all_k(const float* __restrict__ s0, const float* __restrict__ s1,
                                const float* __restrict__ s2, const float* __restrict__ s3,
                                const float* __restrict__ s4, const float* __restrict__ s5,
                                const float* __restrict__ s6, const float* __restrict__ s7,
                                unsigned short* __restrict__ d0, unsigned short* __restrict__ d1,
                                unsigned short* __restrict__ d2, unsigned short* __restrict__ d3,
                                unsigned short* __restrict__ d4, unsigned short* __restrict__ d5,
                                unsigned short* __restrict__ d6, unsigned short* __restrict__ d7) {
    __shared__ float tile[32][33];
    int idx = blockIdx.x;
    const float* W; unsigned short* Wt; int K, N, bx, by;
    if (idx < 6144) {
        int which = idx >> 10, t = idx & 1023;
        bx = t & 31; by = t >> 5; K = 1024; N = 1024;
        switch (which) {
            case 0: W = s0; Wt = d0; break;
            case 1: W = s1; Wt = d1; break;
            case 2: W = s2; Wt = d2; break;
            case 3: W = s3; Wt = d3; break;
            case 4: W = s4; Wt = d4; break;
            default: W = s5; Wt = d5; break;
        }
    } else if (idx < 10240) {
        int t = idx - 6144;
        bx = t & 127; by = t >> 7; K = 1024; N = 4096;
        W = s6; Wt = d6;
    } else {
        int t = idx - 10240;
        bx = t & 31; by = t >> 5; K = 4096; N = 1024;
        W = s7; Wt = d7;
    }
    int k0 = by * 32, n0 = bx * 32;
    int tx = threadIdx.x, ty = threadIdx.y; // 32 x 8
#pragma unroll
    for (int i = 0; i < 32; i += 8)
        tile[ty + i][tx] = W[(long)(k0 + ty + i) * N + n0 + tx];
    __syncthreads();
#pragma unroll
    for (int i = 0; i < 32; i += 8)
        Wt[(long)(n0 + ty + i) * K + k0 + tx] = f2bf(tile[tx][ty + i]);
}

// ---------------- fused Q+K head split with XOR-8 group swizzle ----------------
__global__ __launch_bounds__(256) void split_qk_k(const unsigned short* __restrict__ inQ,
                                                  const unsigned short* __restrict__ inK,
                                                  int stride, int koff,
                                                  unsigned short* __restrict__ Qout,
                                                  unsigned short* __restrict__ Kout) {
    __shared__ __align__(16) unsigned short t[16][1024];
    long l0 = (long)blockIdx.x * 16;
    int tid = threadIdx.x;
    int h = tid >> 4, lr = tid & 15;
    long l = l0 + lr;
    int b = (int)(l >> 11);
    int ll = (int)(l & 2047);
    int sw = ll & 7;

    for (int c = tid; c < 2048; c += 256) {
        int r = c >> 7, col = (c & 127) * 8;
        *(uint4*)(&t[r][col]) = *(const uint4*)(inQ + (l0 + r) * stride + col);
    }
    __syncthreads();
    {
        unsigned short* op = Qout + ((long)(b * 16 + h) * 2048 + ll) * 64;
#pragma unroll
        for (int g = 0; g < 8; g++) {
            union { uint4 v; unsigned short s[8]; } u;
#pragma unroll
            for (int j = 0; j < 8; j++) u.s[j] = t[lr][(g * 8 + j) * 16 + h];
            *(uint4*)(op + (g ^ sw) * 8) = u.v;
        }
    }
    __syncthreads();
    for (int c = tid; c < 2048; c += 256) {
        int r = c >> 7, col = (c & 127) * 8;
        *(uint4*)(&t[r][col]) = *(const uint4*)(inK + (l0 + r) * stride + koff + col);
    }
    __syncthreads();
    {
        unsigned short* op = Kout + ((long)(b * 16 + h) * 2048 + ll) * 64;
#pragma unroll
        for (int g = 0; g < 8; g++) {
            union { uint4 v; unsigned short s[8]; } u;
#pragma unroll
            for (int j = 0; j < 8; j++) u.s[j] = t[lr][(g * 8 + j) * 16 + h];
            *(uint4*)(op + (g ^ sw) * 8) = u.v;
        }
    }
}

// ---------------- per-head transpose + m-perm, deswizzle-in / swizzle-out ----------------
__global__ __launch_bounds__(256) void transpose_heads_perm_k(const unsigned short* __restrict__ in,
                                                              unsigned short* __restrict__ out) {
    __shared__ unsigned short t[64][72];
    int bh = blockIdx.y;
    int m0 = blockIdx.x * 64;
    int tid = threadIdx.x;
    for (int c = tid; c < 512; c += 256) {
        int r = c >> 3, gp = c & 7;
        int glog = gp ^ (r & 7);
        uint4 v = *(const uint4*)(in + ((long)bh * 2048 + m0 + r) * 64 + gp * 8);
        *(uint4*)(&t[r][glog * 8]) = v;
    }
    __syncthreads();
    for (int c = tid; c < 512; c += 256) {
        int d = c >> 3, pb = (c & 7) * 8;
        union { uint4 v; unsigned short s[8]; } u;
#pragma unroll
        for (int j = 0; j < 8; j++) {
            int p = pb + j;
            int m = (p >> 2) + (p & 3) * 16;
            u.s[j] = t[m][d];
        }
        int gph = (pb >> 3) ^ (d & 7);
        *(uint4*)(out + ((long)bh * 64 + d) * 2048 + m0 + gph * 8) = u.v;
    }
}

// ---------------- GEMM: C(M,N) = A(M,K) @ Bt(N,K)^T, bf16 in, fp32 acc ----------------
// EP: 0 = fp32 out, 2 = bias+gelu -> bf16, 3 = bias -> fp32, 4 = bf16, 6 = bias -> bf16
template <int EP, int BN>
__global__ __launch_bounds__(256) void gemm_k(const unsigned short* __restrict__ A,
                                              const unsigned short* __restrict__ Bt,
                                              void* __restrict__ outp,
                                              const float* __restrict__ bias,
                                              const unsigned short* __restrict__ A2,
                                              const unsigned short* __restrict__ Bt2,
                                              void* __restrict__ out2,
                                              int M, int N, int K) {
    if (blockIdx.z) { A = A2; Bt = Bt2; outp = out2; }
    __shared__ __align__(16) unsigned short As[128 * 32];
    __shared__ __align__(16) unsigned short Bs[BN * 32];
    const int NT = BN / 32;       // MFMA n-tiles per wave
    int tid = threadIdx.x;
    int wave = tid >> 6, lane = tid & 63;
    int wm = wave >> 1, wn = wave & 1;
    int quad = lane >> 4, l16 = lane & 15;
    int bm = blockIdx.y * 128, bn = blockIdx.x * BN;

    f32x4_t acc[4][NT] = {};

    const unsigned short* Ag0 = A + (long)(bm + (tid >> 2)) * K + (tid & 3) * 8;
    const unsigned short* Ag1 = A + (long)(bm + (tid >> 2) + 64) * K + (tid & 3) * 8;
    const unsigned short* Bg0 = Bt + (long)(bn + (tid >> 2)) * K + (tid & 3) * 8;
    const unsigned short* Bg1 = Bt + (long)(bn + (tid >> 2) + 64) * K + (tid & 3) * 8;
    unsigned short* Al0 = As + tid * 8;
    unsigned short* Al1 = As + tid * 8 + 2048;
    unsigned short* Bl0 = Bs + tid * 8;
    unsigned short* Bl1 = Bs + tid * 8 + 2048;

    for (int k0 = 0; k0 < K; k0 += 32) {
        __syncthreads();
        __builtin_amdgcn_global_load_lds(GLB(Ag0 + k0), LDS(Al0), 16, 0, 0);
        __builtin_amdgcn_global_load_lds(GLB(Ag1 + k0), LDS(Al1), 16, 0, 0);
        __builtin_amdgcn_global_load_lds(GLB(Bg0 + k0), LDS(Bl0), 16, 0, 0);
        if (BN == 128)
            __builtin_amdgcn_global_load_lds(GLB(Bg1 + k0), LDS(Bl1), 16, 0, 0);
        __syncthreads();
        bf16x8_t af[4], bfr[NT];
#pragma unroll
        for (int t = 0; t < 4; t++)
            af[t] = *(const bf16x8_t*)(As + (wm * 64 + t * 16 + l16) * 32 + quad * 8);
#pragma unroll
        for (int t = 0; t < NT; t++)
            bfr[t] = *(const bf16x8_t*)(Bs + (wn * (BN / 2) + t * 16 + l16) * 32 + quad * 8);
#pragma unroll
        for (int mt = 0; mt < 4; mt++)
#pragma unroll
            for (int nt = 0; nt < NT; nt++)
                acc[mt][nt] = __builtin_amdgcn_mfma_f32_16x16x32_bf16(af[mt], bfr[nt], acc[mt][nt], 0, 0, 0);
    }

#pragma unroll
    for (int mt = 0; mt < 4; mt++)
#pragma unroll
        for (int nt = 0; nt < NT; nt++)
#pragma unroll
            for (int r = 0; r < 4; r++) {
                int gm = bm + wm * 64 + mt * 16 + quad * 4 + r;
                int gn = bn + wn * (BN / 2) + nt * 16 + l16;
                float v = acc[mt][nt][r];
                if (EP == 0) {
                    ((float*)outp)[(long)gm * N + gn] = v;
                } else if (EP == 2) {
                    v += bias[gn];
                    v = 0.5f * v * (1.0f + erff(v * 0.70710678118654752f));
                    ((unsigned short*)outp)[(long)gm * N + gn] = f2bf(v);
                } else if (EP == 3) {
                    ((float*)outp)[(long)gm * N + gn] = v + bias[gn];
                } else if (EP == 6) {
                    ((unsigned short*)outp)[(long)gm * N + gn] = f2bf(v + bias[gn]);
                } else {
                    ((unsigned short*)outp)[(long)gm * N + gn] = f2bf(v);
                }
            }
}

// ---------------- flash attention v8: Q-tile 128, 32 MFMA/tile/wave, 32KB LDS ----------------
// Qh, Kh: [bh][2048][64] swizzled; KhTp: [bh][64][2048] perm+swizzled.
// mask4: [b][t][l16][nt] floats (0 or -1e10). out: [4096][1024] bf16 (col=d*16+h).
// LDS = K1 8K + K2 8K + Ps 16K = 32768. grid 512 -> 2 blk/CU.
template <int USE_MASK>
__global__ __launch_bounds__(256) void flash_attn8_k(const unsigned short* __restrict__ Qh,
                                                     const unsigned short* __restrict__ Kh,
                                                     const unsigned short* __restrict__ KhTp,
                                                     const float* __restrict__ mask4,
                                                     unsigned short* __restrict__ out) {
    __shared__ __align__(16) unsigned short K1[64 * 64];  // [m][d] swizzled groups
    __shared__ __align__(16) unsigned short K2[64 * 64];  // [d][p] swizzled groups
    __shared__ __align__(16) unsigned short Ps[128 * 64]; // [l][p] XOR-8 row-swizzled

    int tid = threadIdx.x;
    int wave = tid >> 6, lane = tid & 63;
    int quad = lane >> 4, l16 = lane & 15;
    int bh = blockIdx.y, b = bh >> 4, h = bh & 15;
    int l0 = blockIdx.x * 128;
    const unsigned short* k1p = Kh + (long)bh * 2048 * 64 + tid * 8;
    const unsigned short* k2p = KhTp + (long)bh * 64 * 2048 + (long)(tid >> 3) * 2048 + (tid & 7) * 8;
    const float* m4p = mask4 + b * 2048 + l16 * 4;

    int sw = l16 & 7;

    // Q fragments in registers for the whole kernel (2 bands of 16 rows per wave)
    bf16x8_t qf[2][2];
#pragma unroll
    for (int mt = 0; mt < 2; mt++) {
        const unsigned short* qrow = Qh + ((long)bh * 2048 + l0 + wave * 32 + mt * 16 + l16) * 64;
#pragma unroll
        for (int kk = 0; kk < 2; kk++)
            qf[mt][kk] = *(const bf16x8_t*)(qrow + ((kk * 4 + quad) ^ sw) * 8);
    }

    const float C1 = 0.125f * LOG2E;
    f32x4_t acc_o[2][4] = {};
    float rs[2][4] = {};

    for (int t = 0; t < 32; ++t) {
        __syncthreads();   // all waves done reading previous tile
        __builtin_amdgcn_global_load_lds(GLB(k1p), LDS(K1 + tid * 8), 16, 0, 0);
        __builtin_amdgcn_global_load_lds(GLB(k1p + 2048), LDS(K1 + tid * 8 + 2048), 16, 0, 0);
        __builtin_amdgcn_global_load_lds(GLB(k2p), LDS(K2 + tid * 8), 16, 0, 0);
        __builtin_amdgcn_global_load_lds(GLB(k2p + 32 * 2048), LDS(K2 + tid * 8 + 2048), 16, 0, 0);
        float4 mq = make_float4(0.f, 0.f, 0.f, 0.f);
        if (USE_MASK) mq = *(const float4*)(m4p + t * 64);
        __syncthreads();   // staging complete

        // S = Q @ Ktile^T : wave handles 32 Q rows (2 bands), 64 m cols
        f32x4_t sacc[2][4] = {};
#pragma unroll
        for (int kk = 0; kk < 2; kk++) {
            int xg = ((kk * 4 + quad) ^ sw) * 8;
#pragma unroll
            for (int nt = 0; nt < 4; nt++) {
                bf16x8_t bfr = *(const bf16x8_t*)(K1 + (nt * 16 + l16) * 64 + xg);
#pragma unroll
                for (int mt = 0; mt < 2; mt++)
                    sacc[mt][nt] = __builtin_amdgcn_mfma_f32_16x16x32_bf16(qf[mt][kk], bfr, sacc[mt][nt], 0, 0, 0);
            }
        }

        // p = exp2(s*C1 + mf); per-lane row-sum; write P 8B (4 bf16, permuted cols, swizzled)
#pragma unroll
        for (int mt = 0; mt < 2; mt++)
#pragma unroll
            for (int r = 0; r < 4; r++) {
                float p0 = exp2f(fmaf(sacc[mt][0][r], C1, mq.x));
                float p1 = exp2f(fmaf(sacc[mt][1][r], C1, mq.y));
                float p2 = exp2f(fmaf(sacc[mt][2][r], C1, mq.z));
                float p3 = exp2f(fmaf(sacc[mt][3][r], C1, mq.w));
                rs[mt][r] += (p0 + p1) + (p2 + p3);
                uint2 pk; pk.x = pack2bf(p0, p1); pk.y = pack2bf(p2, p3);
                int Rrow = wave * 32 + mt * 16 + quad * 4 + r;
                int grp = (l16 >> 1) ^ (Rrow & 7);
                *(uint2*)(Ps + Rrow * 64 + grp * 8 + (l16 & 1) * 4) = pk;
            }

        // O += P @ Ktile : A = own bands of Ps (swizzled), B = K2 (swizzled)
#pragma unroll
        for (int kk = 0; kk < 2; kk++) {
            int xg = ((kk * 4 + quad) ^ sw) * 8;
            int pg = ((kk * 4 + quad) ^ (l16 & 7)) * 8;
            bf16x8_t af0 = *(const bf16x8_t*)(Ps + (wave * 32 + l16) * 64 + pg);
            bf16x8_t af1 = *(const bf16x8_t*)(Ps + (wave * 32 + 16 + l16) * 64 + pg);
#pragma unroll
            for (int nt = 0; nt < 4; nt++) {
                bf16x8_t bfr = *(const bf16x8_t*)(K2 + (nt * 16 + l16) * 64 + xg);
                acc_o[0][nt] = __builtin_amdgcn_mfma_f32_16x16x32_bf16(af0, bfr, acc_o[0][nt], 0, 0, 0);
                acc_o[1][nt] = __builtin_amdgcn_mfma_f32_16x16x32_bf16(af1, bfr, acc_o[1][nt], 0, 0, 0);
            }
        }
        k1p += 4096;
        k2p += 64;
    }

    // single final reduction of row sums across the 16 l16 lanes
#pragma unroll
    for (int mt = 0; mt < 2; mt++)
#pragma unroll
        for (int r = 0; r < 4; r++) {
#pragma unroll
            for (int d = 1; d < 16; d <<= 1) rs[mt][r] += __shfl_xor(rs[mt][r], d);
        }

#pragma unroll
    for (int mt = 0; mt < 2; mt++)
#pragma unroll
        for (int r = 0; r < 4; r++) {
            float inv = 1.0f / rs[mt][r];
            int l = l0 + wave * 32 + mt * 16 + quad * 4 + r;
#pragma unroll
            for (int nt = 0; nt < 4; nt++) {
                int d = nt * 16 + l16;
                out[((long)(b * 2048 + l)) * 1024 + d * 16 + h] = f2bf(acc_o[mt][nt][r] * inv);
            }
        }
}

// ---------------- residual + layernorm: out = LN(a + rb) * g + b  (rb is bf16) ----------------
__global__ __launch_bounds__(256) void resid_ln_k(const float* __restrict__ a,
                                                  const unsigned short* __restrict__ rb,
                                                  const float* __restrict__ g,
                                                  const float* __restrict__ bb,
                                                  float* __restrict__ outf,
                                                  unsigned short* __restrict__ outb) {
    long row = blockIdx.x;
    int tid = threadIdx.x;
    float4 va = ((const float4*)(a + row * 1024))[tid];
    ushort4 vr = ((const ushort4*)(rb + row * 1024))[tid];
    float x0 = va.x + bf2f(vr.x), x1 = va.y + bf2f(vr.y);
    float x2 = va.z + bf2f(vr.z), x3 = va.w + bf2f(vr.w);
    float s = x0 + x1 + x2 + x3;
    float sq = x0 * x0 + x1 * x1 + x2 * x2 + x3 * x3;
#pragma unroll
    for (int d = 1; d < 64; d <<= 1) { s += __shfl_xor(s, d); sq += __shfl_xor(sq, d); }
    __shared__ float ss[4], ssq[4];
    int wave = tid >> 6, lane = tid & 63;
    if (lane == 0) { ss[wave] = s; ssq[wave] = sq; }
    __syncthreads();
    s = ss[0] + ss[1] + ss[2] + ss[3];
    sq = ssq[0] + ssq[1] + ssq[2] + ssq[3];
    float mean = s * (1.0f / 1024.0f);
    float var = sq * (1.0f / 1024.0f) - mean * mean;
    float rstd = rsqrtf(var + 1e-5f);
    float4 vg = ((const float4*)g)[tid];
    float4 vb = ((const float4*)bb)[tid];
    float y0 = (x0 - mean) * rstd * vg.x + vb.x;
    float y1 = (x1 - mean) * rstd * vg.y + vb.y;
    float y2 = (x2 - mean) * rstd * vg.z + vb.z;
    float y3 = (x3 - mean) * rstd * vg.w + vb.w;
    float4 o; o.x = y0; o.y = y1; o.z = y2; o.w = y3;
    ((float4*)(outf + row * 1024))[tid] = o;
    ushort4 ob; ob.x = f2bf(y0); ob.y = f2bf(y1); ob.z = f2bf(y2); ob.w = f2bf(y3);
    ((ushort4*)(outb + row * 1024))[tid] = ob;
}

extern "C" void kernel_launch(void* const* d_in, const int* in_sizes, int n_in,
                              void* d_out, int out_size, void* d_ws, size_t ws_size,
                              hipStream_t stream) {
    const float* x    = (const float*)d_in[0];
    const float* enc  = (const float*)d_in[1];
    const int*   mask = (const int*)d_in[2];
    const float* q1W  = (const float*)d_in[3];
    const float* w1W  = (const float*)d_in[4];
    const float* o1W  = (const float*)d_in[5];
    const float* q2W  = (const float*)d_in[6];
    const float* w2W  = (const float*)d_in[7];
    const float* o2W  = (const float*)d_in[8];
    const float* ffW1 = (const float*)d_in[9];
    const float* ffb1 = (const float*)d_in[10];
    const float* ffW2 = (const float*)d_in[11];
    const float* ffb2 = (const float*)d_in[12];
    const float* g1 = (const float*)d_in[13];
    const float* b1 = (const float*)d_in[14];
    const float* g2 = (const float*)d_in[15];
    const float* b2 = (const float*)d_in[16];
    const float* g3 = (const float*)d_in[17];
    const float* b3 = (const float*)d_in[18];
    float* outp = (float*)d_out;

    const int T = 4096;   // B*L
    const int D = 1024;
    const int F = 4096;   // MLP

    char* ws = (char*)d_ws;
    auto alloc = [&](size_t sz) { char* p = ws; ws += (sz + 255) & ~(size_t)255; return p; };
    unsigned short* qw1Wt = (unsigned short*)alloc((size_t)2 * D * D * 2); // fused [2048][1024]
    unsigned short* o1Wt  = (unsigned short*)alloc((size_t)D * D * 2);
    unsigned short* q2Wt  = (unsigned short*)alloc((size_t)D * D * 2);
    unsigned short* w2Wt  = (unsigned short*)alloc((size_t)D * D * 2);
    unsigned short* o2Wt  = (unsigned short*)alloc((size_t)D * D * 2);
    unsigned short* ffW1t = (unsigned short*)alloc((size_t)F * D * 2);
    unsigned short* ffW2t = (unsigned short*)alloc((size_t)D * F * 2);
    unsigned short* xb    = (unsigned short*)alloc((size_t)T * D * 2);
    unsigned short* encb  = (unsigned short*)alloc((size_t)T * D * 2);
    unsigned short* Qhb   = (unsigned short*)alloc((size_t)T * D * 2);
    unsigned short* Khb   = (unsigned short*)alloc((size_t)T * D * 2);
    unsigned short* KhTb  = (unsigned short*)alloc((size_t)T * D * 2);
    unsigned short* attnb = (unsigned short*)alloc((size_t)T * D * 2);
    float*          mask4b= (float*)alloc((size_t)8192 * 4);
    unsigned short* projb = (unsigned short*)alloc((size_t)T * D * 2);
    float*          x1f   = (float*)alloc((size_t)T * D * 4);
    unsigned short* x1b   = (unsigned short*)alloc((size_t)T * D * 2);
    float*          x2f   = (float*)alloc((size_t)T * D * 4);
    unsigned short* x2b   = (unsigned short*)alloc((size_t)T * D * 2);
    unsigned short* S1    = (unsigned short*)alloc((size_t)T * F * 2); // 32 MB scratch
    unsigned short* tmpqw = S1;                 // [4096][2048]
    unsigned short* q2o   = S1;                 // [4096][1024]
    unsigned short* w2o   = S1 + (size_t)T * D; // [4096][1024]
    unsigned short* hb    = S1;                 // [4096][4096]

    dim3 blk256(256);
    dim3 tblk(32, 8);

    // prologue: fused casts (+ mask4 prep) + fused weight transposes
    cast2_bf16_k<<<dim3(T * D / 4 / 256, 3), blk256, 0, stream>>>(x, xb, enc, encb, T * D / 4, mask, mask4b);
    transpose_all_k<<<dim3(14336), tblk, 0, stream>>>(
        q1W, w1W, o1W, q2W, w2W, o2W, ffW1, ffW2,
        qw1Wt, qw1Wt + (size_t)D * D, o1Wt, q2Wt, w2Wt, o2Wt, ffW1t, ffW2t);

    // ---- self attention ----
    gemm_k<4, 128><<<dim3(2 * D / 128, T / 128, 1), blk256, 0, stream>>>(
        xb, qw1Wt, tmpqw, nullptr, nullptr, nullptr, nullptr, T, 2 * D, D);
    split_qk_k<<<dim3(T / 16), blk256, 0, stream>>>(tmpqw, tmpqw, 2 * D, D, Qhb, Khb);
    transpose_heads_perm_k<<<dim3(32, 32), blk256, 0, stream>>>(Khb, KhTb);
    flash_attn8_k<0><<<dim3(16, 32), blk256, 0, stream>>>(Qhb, Khb, KhTb, nullptr, attnb);
    gemm_k<4, 64><<<dim3(D / 64, T / 128, 1), blk256, 0, stream>>>(
        attnb, o1Wt, projb, nullptr, nullptr, nullptr, nullptr, T, D, D);
    resid_ln_k<<<dim3(T), blk256, 0, stream>>>(x, projb, g1, b1, x1f, x1b);

    // ---- cross attention ----
    gemm_k<4, 64><<<dim3(D / 64, T / 128, 2), blk256, 0, stream>>>(
        x1b, q2Wt, q2o, nullptr, encb, w2Wt, w2o, T, D, D);
    split_qk_k<<<dim3(T / 16), blk256, 0, stream>>>(q2o, w2o, D, 0, Qhb, Khb);
    transpose_heads_perm_k<<<dim3(32, 32), blk256, 0, stream>>>(Khb, KhTb);
    flash_attn8_k<1><<<dim3(16, 32), blk256, 0, stream>>>(Qhb, Khb, KhTb, mask4b, attnb);
    gemm_k<4, 64><<<dim3(D / 64, T / 128, 1), blk256, 0, stream>>>(
        attnb, o2Wt, projb, nullptr, nullptr, nullptr, nullptr, T, D, D);
    resid_ln_k<<<dim3(T), blk256, 0, stream>>>(x1f, projb, g2, b2, x2f, x2b);

    // ---- feed forward ----
    gemm_k<2, 128><<<dim3(F / 128, T / 128, 1), blk256, 0, stream>>>(
        x2b, ffW1t, hb, ffb1, nullptr, nullptr, nullptr, T, F, D);
    gemm_k<6, 64><<<dim3(D / 64, T / 128, 1), blk256, 0, stream>>>(
        hb, ffW2t, projb, ffb2, nullptr, nullptr, nullptr, T, D, F);
    resid_ln_k<<<dim3(T), blk256, 0, stream>>>(x2f, projb, g3, b3, outp, x2b);
}

// Round 9
// 621.001 us; speedup vs baseline: 1.0438x; 1.0438x over previous
//
#include <hip/hip_runtime.h>
#include <hip/hip_bf16.h>
#include <math.h>
#include <stdint.h>

typedef __attribute__((ext_vector_type(8))) short bf16x8_t;
typedef __attribute__((ext_vector_type(4))) float f32x4_t;

#define LOG2E 1.4426950408889634f
#define GLB(p) ((const __attribute__((address_space(1))) void*)(p))
#define LDS(p) ((__attribute__((address_space(3))) void*)(p))

__device__ __forceinline__ unsigned short f2bf(float f) {
    union { float f; unsigned int u; } v; v.f = f;
    unsigned int r = v.u + 0x7FFFu + ((v.u >> 16) & 1u);
    return (unsigned short)(r >> 16);
}

__device__ __forceinline__ float bf2f(unsigned short us) {
    union { unsigned int u; float f; } c; c.u = (unsigned int)us << 16; return c.f;
}

__device__ __forceinline__ unsigned int pack2bf(float a, float b) {
#if __has_builtin(__builtin_amdgcn_cvt_pk_bf16_f32)
    auto r = __builtin_amdgcn_cvt_pk_bf16_f32(a, b);
    unsigned int u;
    __builtin_memcpy(&u, &r, 4);
    return u;
#else
    return (unsigned int)f2bf(a) | ((unsigned int)f2bf(b) << 16);
#endif
}

// ---------------- fused cast fp32 -> bf16 for x, enc + mask4 prep ----------------
// mask4[b][t][l16][nt] = maskp[b*2048 + t*64 + nt*16 + l16] ? -1e10 : 0  (8192 floats)
__global__ void cast2_bf16_k(const float* __restrict__ inA, unsigned short* __restrict__ outA,
                             const float* __restrict__ inB, unsigned short* __restrict__ outB,
                             int n4, const int* __restrict__ maskp, float* __restrict__ mask4) {
    if (blockIdx.y == 2) {
        int i = blockIdx.x * blockDim.x + threadIdx.x;
        if (i < 8192) {
            int nt = i & 3, l16 = (i >> 2) & 15, t = (i >> 6) & 31, b = (i >> 11) & 1;
            mask4[i] = maskp[b * 2048 + t * 64 + nt * 16 + l16] ? -1e10f : 0.0f;
        }
        return;
    }
    const float* in = blockIdx.y ? inB : inA;
    unsigned short* out = blockIdx.y ? outB : outA;
    int i = blockIdx.x * blockDim.x + threadIdx.x;
    if (i < n4) {
        float4 v = ((const float4*)in)[i];
        ushort4 o;
        o.x = f2bf(v.x); o.y = f2bf(v.y); o.z = f2bf(v.z); o.w = f2bf(v.w);
        ((ushort4*)out)[i] = o;
    }
}

// ---------------- fused weight transpose+cast: all 8 weights in one dispatch ----------------
__global__ void transpose_all_k(const float* __restrict__ s0, const float* __restrict__ s1,
                                const float* __restrict__ s2, const float* __restrict__ s3,
                                const float* __restrict__ s4, const float* __restrict__ s5,
                                const float* __restrict__ s6, const float* __restrict__ s7,
                                unsigned short* __restrict__ d0, unsigned short* __restrict__ d1,
                                unsigned short* __restrict__ d2, unsigned short* __restrict__ d3,
                                unsigned short* __restrict__ d4, unsigned short* __restrict__ d5,
                                unsigned short* __restrict__ d6, unsigned short* __restrict__ d7) {
    __shared__ float tile[32][33];
    int idx = blockIdx.x;
    const float* W; unsigned short* Wt; int K, N, bx, by;
    if (idx < 6144) {
        int which = idx >> 10, t = idx & 1023;
        bx = t & 31; by = t >> 5; K = 1024; N = 1024;
        switch (which) {
            case 0: W = s0; Wt = d0; break;
            case 1: W = s1; Wt = d1; break;
            case 2: W = s2; Wt = d2; break;
            case 3: W = s3; Wt = d3; break;
            case 4: W = s4; Wt = d4; break;
            default: W = s5; Wt = d5; break;
        }
    } else if (idx < 10240) {
        int t = idx - 6144;
        bx = t & 127; by = t >> 7; K = 1024; N = 4096;
        W = s6; Wt = d6;
    } else {
        int t = idx - 10240;
        bx = t & 31; by = t >> 5; K = 4096; N = 1024;
        W = s7; Wt = d7;
    }
    int k0 = by * 32, n0 = bx * 32;
    int tx = threadIdx.x, ty = threadIdx.y; // 32 x 8
#pragma unroll
    for (int i = 0; i < 32; i += 8)
        tile[ty + i][tx] = W[(long)(k0 + ty + i) * N + n0 + tx];
    __syncthreads();
#pragma unroll
    for (int i = 0; i < 32; i += 8)
        Wt[(long)(n0 + ty + i) * K + k0 + tx] = f2bf(tile[tx][ty + i]);
}

// ---------------- fused Q+K head split with XOR-8 group swizzle ----------------
__global__ __launch_bounds__(256) void split_qk_k(const unsigned short* __restrict__ inQ,
                                                  const unsigned short* __restrict__ inK,
                                                  int stride, int koff,
                                                  unsigned short* __restrict__ Qout,
                                                  unsigned short* __restrict__ Kout) {
    __shared__ __align__(16) unsigned short t[16][1024];
    long l0 = (long)blockIdx.x * 16;
    int tid = threadIdx.x;
    int h = tid >> 4, lr = tid & 15;
    long l = l0 + lr;
    int b = (int)(l >> 11);
    int ll = (int)(l & 2047);
    int sw = ll & 7;

    for (int c = tid; c < 2048; c += 256) {
        int r = c >> 7, col = (c & 127) * 8;
        *(uint4*)(&t[r][col]) = *(const uint4*)(inQ + (l0 + r) * stride + col);
    }
    __syncthreads();
    {
        unsigned short* op = Qout + ((long)(b * 16 + h) * 2048 + ll) * 64;
#pragma unroll
        for (int g = 0; g < 8; g++) {
            union { uint4 v; unsigned short s[8]; } u;
#pragma unroll
            for (int j = 0; j < 8; j++) u.s[j] = t[lr][(g * 8 + j) * 16 + h];
            *(uint4*)(op + (g ^ sw) * 8) = u.v;
        }
    }
    __syncthreads();
    for (int c = tid; c < 2048; c += 256) {
        int r = c >> 7, col = (c & 127) * 8;
        *(uint4*)(&t[r][col]) = *(const uint4*)(inK + (l0 + r) * stride + koff + col);
    }
    __syncthreads();
    {
        unsigned short* op = Kout + ((long)(b * 16 + h) * 2048 + ll) * 64;
#pragma unroll
        for (int g = 0; g < 8; g++) {
            union { uint4 v; unsigned short s[8]; } u;
#pragma unroll
            for (int j = 0; j < 8; j++) u.s[j] = t[lr][(g * 8 + j) * 16 + h];
            *(uint4*)(op + (g ^ sw) * 8) = u.v;
        }
    }
}

// ---------------- per-head transpose + m-perm, deswizzle-in / swizzle-out ----------------
__global__ __launch_bounds__(256) void transpose_heads_perm_k(const unsigned short* __restrict__ in,
                                                              unsigned short* __restrict__ out) {
    __shared__ unsigned short t[64][72];
    int bh = blockIdx.y;
    int m0 = blockIdx.x * 64;
    int tid = threadIdx.x;
    for (int c = tid; c < 512; c += 256) {
        int r = c >> 3, gp = c & 7;
        int glog = gp ^ (r & 7);
        uint4 v = *(const uint4*)(in + ((long)bh * 2048 + m0 + r) * 64 + gp * 8);
        *(uint4*)(&t[r][glog * 8]) = v;
    }
    __syncthreads();
    for (int c = tid; c < 512; c += 256) {
        int d = c >> 3, pb = (c & 7) * 8;
        union { uint4 v; unsigned short s[8]; } u;
#pragma unroll
        for (int j = 0; j < 8; j++) {
            int p = pb + j;
            int m = (p >> 2) + (p & 3) * 16;
            u.s[j] = t[m][d];
        }
        int gph = (pb >> 3) ^ (d & 7);
        *(uint4*)(out + ((long)bh * 64 + d) * 2048 + m0 + gph * 8) = u.v;
    }
}

// ---------------- GEMM v2: BK=64, XOR-swizzled staging, 2-way-free fragment reads ----------
// C(M,N) = A(M,K) @ Bt(N,K)^T, bf16 in, fp32 acc.
// EP: 0 = fp32 out, 2 = bias+gelu -> bf16, 3 = bias -> fp32, 4 = bf16, 6 = bias -> bf16
template <int EP, int BN>
__global__ __launch_bounds__(256) void gemm_k(const unsigned short* __restrict__ A,
                                              const unsigned short* __restrict__ Bt,
                                              void* __restrict__ outp,
                                              const float* __restrict__ bias,
                                              const unsigned short* __restrict__ A2,
                                              const unsigned short* __restrict__ Bt2,
                                              void* __restrict__ out2,
                                              int M, int N, int K) {
    if (blockIdx.z) { A = A2; Bt = Bt2; outp = out2; }
    __shared__ __align__(16) unsigned short As[128 * 64];
    __shared__ __align__(16) unsigned short Bs[BN * 64];
    const int NT = BN / 32;       // MFMA n-tiles per wave
    const int BG = BN / 32;       // B staging GLDS ops
    int tid = threadIdx.x;
    int wave = tid >> 6, lane = tid & 63;
    int wm = wave >> 1, wn = wave & 1;
    int quad = lane >> 4, l16 = lane & 15;
    int bm = blockIdx.y * 128, bn = blockIdx.x * BN;

    f32x4_t acc[4][NT] = {};

    // staging: thread t covers row i*32 + (t>>3); physical group (t&7) holds
    // logical k-group (t&7)^(row&7)  -> source col = ((t&7)^(row&7))*8
    int srow = tid >> 3;
    int sgrp = (tid & 7) ^ (srow & 7);
    const unsigned short* Ag[4];
#pragma unroll
    for (int i = 0; i < 4; i++)
        Ag[i] = A + (long)(bm + i * 32 + srow) * K + sgrp * 8;
    const unsigned short* Bg[BG];
#pragma unroll
    for (int i = 0; i < BG; i++)
        Bg[i] = Bt + (long)(bn + i * 32 + srow) * K + sgrp * 8;

    for (int k0 = 0; k0 < K; k0 += 64) {
        __syncthreads();
#pragma unroll
        for (int i = 0; i < 4; i++)
            __builtin_amdgcn_global_load_lds(GLB(Ag[i] + k0), LDS(As + i * 2048 + tid * 8), 16, 0, 0);
#pragma unroll
        for (int i = 0; i < BG; i++)
            __builtin_amdgcn_global_load_lds(GLB(Bg[i] + k0), LDS(Bs + i * 2048 + tid * 8), 16, 0, 0);
        __syncthreads();
#pragma unroll
        for (int kk = 0; kk < 2; kk++) {
            int xg = ((kk * 4 + quad) ^ (l16 & 7)) * 8;
            bf16x8_t af[4], bfr[NT];
#pragma unroll
            for (int t = 0; t < 4; t++)
                af[t] = *(const bf16x8_t*)(As + (wm * 64 + t * 16 + l16) * 64 + xg);
#pragma unroll
            for (int t = 0; t < NT; t++)
                bfr[t] = *(const bf16x8_t*)(Bs + (wn * (BN / 2) + t * 16 + l16) * 64 + xg);
#pragma unroll
            for (int mt = 0; mt < 4; mt++)
#pragma unroll
                for (int nt = 0; nt < NT; nt++)
                    acc[mt][nt] = __builtin_amdgcn_mfma_f32_16x16x32_bf16(af[mt], bfr[nt], acc[mt][nt], 0, 0, 0);
        }
    }

#pragma unroll
    for (int mt = 0; mt < 4; mt++)
#pragma unroll
        for (int nt = 0; nt < NT; nt++)
#pragma unroll
            for (int r = 0; r < 4; r++) {
                int gm = bm + wm * 64 + mt * 16 + quad * 4 + r;
                int gn = bn + wn * (BN / 2) + nt * 16 + l16;
                float v = acc[mt][nt][r];
                if (EP == 0) {
                    ((float*)outp)[(long)gm * N + gn] = v;
                } else if (EP == 2) {
                    v += bias[gn];
                    v = 0.5f * v * (1.0f + erff(v * 0.70710678118654752f));
                    ((unsigned short*)outp)[(long)gm * N + gn] = f2bf(v);
                } else if (EP == 3) {
                    ((float*)outp)[(long)gm * N + gn] = v + bias[gn];
                } else if (EP == 6) {
                    ((unsigned short*)outp)[(long)gm * N + gn] = f2bf(v + bias[gn]);
                } else {
                    ((unsigned short*)outp)[(long)gm * N + gn] = f2bf(v);
                }
            }
}

// ---------------- flash attention v7 (reverted; measured 90.5us): 24576B LDS ----------------
// Qh, Kh: [bh][2048][64] swizzled; KhTp: [bh][64][2048] perm+swizzled.
// mask4: [b][t][l16][nt] floats (0 or -1e10). out: [4096][1024] bf16 (col=d*16+h).
template <int USE_MASK>
__global__ __launch_bounds__(256, 4) void flash_attn7_k(const unsigned short* __restrict__ Qh,
                                                        const unsigned short* __restrict__ Kh,
                                                        const unsigned short* __restrict__ KhTp,
                                                        const float* __restrict__ mask4,
                                                        unsigned short* __restrict__ out) {
    __shared__ __align__(16) unsigned short K1[64 * 64]; // [m][d] swizzled groups
    __shared__ __align__(16) unsigned short K2[64 * 64]; // [d][p] swizzled groups
    __shared__ __align__(16) unsigned short Ps[64 * 64]; // [l][p] XOR-8 row-swizzled

    int tid = threadIdx.x;
    int wave = tid >> 6, lane = tid & 63;
    int quad = lane >> 4, l16 = lane & 15;
    int bh = blockIdx.y, b = bh >> 4, h = bh & 15;
    int l0 = blockIdx.x * 64;
    const unsigned short* k1p = Kh + (long)bh * 2048 * 64 + tid * 8;
    const unsigned short* k2p = KhTp + (long)bh * 64 * 2048 + (long)(tid >> 3) * 2048 + (tid & 7) * 8;
    const float* m4p = mask4 + b * 2048 + l16 * 4;

    int sw = l16 & 7;

    // Q fragments live in registers for the whole kernel (wave-invariant rows)
    const unsigned short* qrow = Qh + ((long)bh * 2048 + l0 + wave * 16 + l16) * 64;
    bf16x8_t qf[2];
#pragma unroll
    for (int kk = 0; kk < 2; kk++)
        qf[kk] = *(const bf16x8_t*)(qrow + ((kk * 4 + quad) ^ sw) * 8);

    const float C1 = 0.125f * LOG2E;
    f32x4_t acc_o[4] = {};
    float rs[4] = {0.f, 0.f, 0.f, 0.f};

    for (int t = 0; t < 32; ++t) {
        __syncthreads();   // all waves done reading previous tile
        __builtin_amdgcn_global_load_lds(GLB(k1p), LDS(K1 + tid * 8), 16, 0, 0);
        __builtin_amdgcn_global_load_lds(GLB(k1p + 2048), LDS(K1 + tid * 8 + 2048), 16, 0, 0);
        __builtin_amdgcn_global_load_lds(GLB(k2p), LDS(K2 + tid * 8), 16, 0, 0);
        __builtin_amdgcn_global_load_lds(GLB(k2p + 32 * 2048), LDS(K2 + tid * 8 + 2048), 16, 0, 0);
        float4 mq = make_float4(0.f, 0.f, 0.f, 0.f);
        if (USE_MASK) mq = *(const float4*)(m4p + t * 64);
        __syncthreads();   // staging complete

        // S = Q @ Ktile^T : wave handles 16 Q rows (band = wave*16), 64 m cols
        f32x4_t sacc[4] = {};
#pragma unroll
        for (int kk = 0; kk < 2; kk++) {
            int xg = ((kk * 4 + quad) ^ sw) * 8;
#pragma unroll
            for (int nt = 0; nt < 4; nt++) {
                bf16x8_t bfr = *(const bf16x8_t*)(K1 + (nt * 16 + l16) * 64 + xg);
                sacc[nt] = __builtin_amdgcn_mfma_f32_16x16x32_bf16(qf[kk], bfr, sacc[nt], 0, 0, 0);
            }
        }

        // p = exp2(s*C1 + mf); per-lane row-sum; write P 8B (4 bf16, permuted cols, swizzled)
#pragma unroll
        for (int r = 0; r < 4; r++) {
            float p0 = exp2f(fmaf(sacc[0][r], C1, mq.x));
            float p1 = exp2f(fmaf(sacc[1][r], C1, mq.y));
            float p2 = exp2f(fmaf(sacc[2][r], C1, mq.z));
            float p3 = exp2f(fmaf(sacc[3][r], C1, mq.w));
            rs[r] += (p0 + p1) + (p2 + p3);
            uint2 pk; pk.x = pack2bf(p0, p1); pk.y = pack2bf(p2, p3);
            int Rrow = wave * 16 + quad * 4 + r;
            int grp = (l16 >> 1) ^ (Rrow & 7);
            *(uint2*)(Ps + Rrow * 64 + grp * 8 + (l16 & 1) * 4) = pk;
        }

        // O += P @ Ktile : A = own band of Ps (swizzled), B = K2 (swizzled)
#pragma unroll
        for (int kk = 0; kk < 2; kk++) {
            int xg = ((kk * 4 + quad) ^ sw) * 8;
            int Rr = wave * 16 + l16;
            int pg = ((kk * 4 + quad) ^ (l16 & 7)) * 8;
            bf16x8_t af = *(const bf16x8_t*)(Ps + Rr * 64 + pg);
#pragma unroll
            for (int nt = 0; nt < 4; nt++) {
                bf16x8_t bfr = *(const bf16x8_t*)(K2 + (nt * 16 + l16) * 64 + xg);
                acc_o[nt] = __builtin_amdgcn_mfma_f32_16x16x32_bf16(af, bfr, acc_o[nt], 0, 0, 0);
            }
        }
        k1p += 4096;
        k2p += 64;
    }

    // single final reduction of row sums across the 16 l16 lanes
#pragma unroll
    for (int r = 0; r < 4; r++) {
#pragma unroll
        for (int d = 1; d < 16; d <<= 1) rs[r] += __shfl_xor(rs[r], d);
    }

#pragma unroll
    for (int r = 0; r < 4; r++) {
        float inv = 1.0f / rs[r];
        int l = l0 + wave * 16 + quad * 4 + r;
#pragma unroll
        for (int nt = 0; nt < 4; nt++) {
            int d = nt * 16 + l16;
            out[((long)(b * 2048 + l)) * 1024 + d * 16 + h] = f2bf(acc_o[nt][r] * inv);
        }
    }
}

// ---------------- residual + layernorm: out = LN(a + rb) * g + b  (rb is bf16) ----------------
__global__ __launch_bounds__(256) void resid_ln_k(const float* __restrict__ a,
                                                  const unsigned short* __restrict__ rb,
                                                  const float* __restrict__ g,
                                                  const float* __restrict__ bb,
                                                  float* __restrict__ outf,
                                                  unsigned short* __restrict__ outb) {
    long row = blockIdx.x;
    int tid = threadIdx.x;
    float4 va = ((const float4*)(a + row * 1024))[tid];
    ushort4 vr = ((const ushort4*)(rb + row * 1024))[tid];
    float x0 = va.x + bf2f(vr.x), x1 = va.y + bf2f(vr.y);
    float x2 = va.z + bf2f(vr.z), x3 = va.w + bf2f(vr.w);
    float s = x0 + x1 + x2 + x3;
    float sq = x0 * x0 + x1 * x1 + x2 * x2 + x3 * x3;
#pragma unroll
    for (int d = 1; d < 64; d <<= 1) { s += __shfl_xor(s, d); sq += __shfl_xor(sq, d); }
    __shared__ float ss[4], ssq[4];
    int wave = tid >> 6, lane = tid & 63;
    if (lane == 0) { ss[wave] = s; ssq[wave] = sq; }
    __syncthreads();
    s = ss[0] + ss[1] + ss[2] + ss[3];
    sq = ssq[0] + ssq[1] + ssq[2] + ssq[3];
    float mean = s * (1.0f / 1024.0f);
    float var = sq * (1.0f / 1024.0f) - mean * mean;
    float rstd = rsqrtf(var + 1e-5f);
    float4 vg = ((const float4*)g)[tid];
    float4 vb = ((const float4*)bb)[tid];
    float y0 = (x0 - mean) * rstd * vg.x + vb.x;
    float y1 = (x1 - mean) * rstd * vg.y + vb.y;
    float y2 = (x2 - mean) * rstd * vg.z + vb.z;
    float y3 = (x3 - mean) * rstd * vg.w + vb.w;
    float4 o; o.x = y0; o.y = y1; o.z = y2; o.w = y3;
    ((float4*)(outf + row * 1024))[tid] = o;
    ushort4 ob; ob.x = f2bf(y0); ob.y = f2bf(y1); ob.z = f2bf(y2); ob.w = f2bf(y3);
    ((ushort4*)(outb + row * 1024))[tid] = ob;
}

extern "C" void kernel_launch(void* const* d_in, const int* in_sizes, int n_in,
                              void* d_out, int out_size, void* d_ws, size_t ws_size,
                              hipStream_t stream) {
    const float* x    = (const float*)d_in[0];
    const float* enc  = (const float*)d_in[1];
    const int*   mask = (const int*)d_in[2];
    const float* q1W  = (const float*)d_in[3];
    const float* w1W  = (const float*)d_in[4];
    const float* o1W  = (const float*)d_in[5];
    const float* q2W  = (const float*)d_in[6];
    const float* w2W  = (const float*)d_in[7];
    const float* o2W  = (const float*)d_in[8];
    const float* ffW1 = (const float*)d_in[9];
    const float* ffb1 = (const float*)d_in[10];
    const float* ffW2 = (const float*)d_in[11];
    const float* ffb2 = (const float*)d_in[12];
    const float* g1 = (const float*)d_in[13];
    const float* b1 = (const float*)d_in[14];
    const float* g2 = (const float*)d_in[15];
    const float* b2 = (const float*)d_in[16];
    const float* g3 = (const float*)d_in[17];
    const float* b3 = (const float*)d_in[18];
    float* outp = (float*)d_out;

    const int T = 4096;   // B*L
    const int D = 1024;
    const int F = 4096;   // MLP

    char* ws = (char*)d_ws;
    auto alloc = [&](size_t sz) { char* p = ws; ws += (sz + 255) & ~(size_t)255; return p; };
    unsigned short* qw1Wt = (unsigned short*)alloc((size_t)2 * D * D * 2); // fused [2048][1024]
    unsigned short* o1Wt  = (unsigned short*)alloc((size_t)D * D * 2);
    unsigned short* q2Wt  = (unsigned short*)alloc((size_t)D * D * 2);
    unsigned short* w2Wt  = (unsigned short*)alloc((size_t)D * D * 2);
    unsigned short* o2Wt  = (unsigned short*)alloc((size_t)D * D * 2);
    unsigned short* ffW1t = (unsigned short*)alloc((size_t)F * D * 2);
    unsigned short* ffW2t = (unsigned short*)alloc((size_t)D * F * 2);
    unsigned short* xb    = (unsigned short*)alloc((size_t)T * D * 2);
    unsigned short* encb  = (unsigned short*)alloc((size_t)T * D * 2);
    unsigned short* Qhb   = (unsigned short*)alloc((size_t)T * D * 2);
    unsigned short* Khb   = (unsigned short*)alloc((size_t)T * D * 2);
    unsigned short* KhTb  = (unsigned short*)alloc((size_t)T * D * 2);
    unsigned short* attnb = (unsigned short*)alloc((size_t)T * D * 2);
    float*          mask4b= (float*)alloc((size_t)8192 * 4);
    unsigned short* projb = (unsigned short*)alloc((size_t)T * D * 2);
    float*          x1f   = (float*)alloc((size_t)T * D * 4);
    unsigned short* x1b   = (unsigned short*)alloc((size_t)T * D * 2);
    float*          x2f   = (float*)alloc((size_t)T * D * 4);
    unsigned short* x2b   = (unsigned short*)alloc((size_t)T * D * 2);
    unsigned short* S1    = (unsigned short*)alloc((size_t)T * F * 2); // 32 MB scratch
    unsigned short* tmpqw = S1;                 // [4096][2048]
    unsigned short* q2o   = S1;                 // [4096][1024]
    unsigned short* w2o   = S1 + (size_t)T * D; // [4096][1024]
    unsigned short* hb    = S1;                 // [4096][4096]

    dim3 blk256(256);
    dim3 tblk(32, 8);

    // prologue: fused casts (+ mask4 prep) + fused weight transposes
    cast2_bf16_k<<<dim3(T * D / 4 / 256, 3), blk256, 0, stream>>>(x, xb, enc, encb, T * D / 4, mask, mask4b);
    transpose_all_k<<<dim3(14336), tblk, 0, stream>>>(
        q1W, w1W, o1W, q2W, w2W, o2W, ffW1, ffW2,
        qw1Wt, qw1Wt + (size_t)D * D, o1Wt, q2Wt, w2Wt, o2Wt, ffW1t, ffW2t);

    // ---- self attention ----
    gemm_k<4, 128><<<dim3(2 * D / 128, T / 128, 1), blk256, 0, stream>>>(
        xb, qw1Wt, tmpqw, nullptr, nullptr, nullptr, nullptr, T, 2 * D, D);
    split_qk_k<<<dim3(T / 16), blk256, 0, stream>>>(tmpqw, tmpqw, 2 * D, D, Qhb, Khb);
    transpose_heads_perm_k<<<dim3(32, 32), blk256, 0, stream>>>(Khb, KhTb);
    flash_attn7_k<0><<<dim3(32, 32), blk256, 0, stream>>>(Qhb, Khb, KhTb, nullptr, attnb);
    gemm_k<4, 64><<<dim3(D / 64, T / 128, 1), blk256, 0, stream>>>(
        attnb, o1Wt, projb, nullptr, nullptr, nullptr, nullptr, T, D, D);
    resid_ln_k<<<dim3(T), blk256, 0, stream>>>(x, projb, g1, b1, x1f, x1b);

    // ---- cross attention ----
    gemm_k<4, 64><<<dim3(D / 64, T / 128, 2), blk256, 0, stream>>>(
        x1b, q2Wt, q2o, nullptr, encb, w2Wt, w2o, T, D, D);
    split_qk_k<<<dim3(T / 16), blk256, 0, stream>>>(q2o, w2o, D, 0, Qhb, Khb);
    transpose_heads_perm_k<<<dim3(32, 32), blk256, 0, stream>>>(Khb, KhTb);
    flash_attn7_k<1><<<dim3(32, 32), blk256, 0, stream>>>(Qhb, Khb, KhTb, mask4b, attnb);
    gemm_k<4, 64><<<dim3(D / 64, T / 128, 1), blk256, 0, stream>>>(
        attnb, o2Wt, projb, nullptr, nullptr, nullptr, nullptr, T, D, D);
    resid_ln_k<<<dim3(T), blk256, 0, stream>>>(x1f, projb, g2, b2, x2f, x2b);

    // ---- feed forward ----
    gemm_k<2, 128><<<dim3(F / 128, T / 128, 1), blk256, 0, stream>>>(
        x2b, ffW1t, hb, ffb1, nullptr, nullptr, nullptr, T, F, D);
    gemm_k<6, 64><<<dim3(D / 64, T / 128, 1), blk256, 0, stream>>>(
        hb, ffW2t, projb, ffb2, nullptr, nullptr, nullptr, T, D, F);
    resid_ln_k<<<dim3(T), blk256, 0, stream>>>(x2f, projb, g3, b3, outp, x2b);
}

// Round 10
// 590.951 us; speedup vs baseline: 1.0969x; 1.0508x over previous
//
#include <hip/hip_runtime.h>
#include <hip/hip_bf16.h>
#include <math.h>
#include <stdint.h>

typedef __attribute__((ext_vector_type(8))) short bf16x8_t;
typedef __attribute__((ext_vector_type(4))) float f32x4_t;

#define LOG2E 1.4426950408889634f
#define GLB(p) ((const __attribute__((address_space(1))) void*)(p))
#define LDS(p) ((__attribute__((address_space(3))) void*)(p))

__device__ __forceinline__ unsigned short f2bf(float f) {
    union { float f; unsigned int u; } v; v.f = f;
    unsigned int r = v.u + 0x7FFFu + ((v.u >> 16) & 1u);
    return (unsigned short)(r >> 16);
}

__device__ __forceinline__ float bf2f(unsigned short us) {
    union { unsigned int u; float f; } c; c.u = (unsigned int)us << 16; return c.f;
}

__device__ __forceinline__ unsigned int pack2bf(float a, float b) {
#if __has_builtin(__builtin_amdgcn_cvt_pk_bf16_f32)
    auto r = __builtin_amdgcn_cvt_pk_bf16_f32(a, b);
    unsigned int u;
    __builtin_memcpy(&u, &r, 4);
    return u;
#else
    return (unsigned int)f2bf(a) | ((unsigned int)f2bf(b) << 16);
#endif
}

__device__ __forceinline__ float fast_rcp(float x) {
#if __has_builtin(__builtin_amdgcn_rcpf)
    return __builtin_amdgcn_rcpf(x);
#else
    return 1.0f / x;
#endif
}

// gelu tanh-form: 0.5x(1+tanh(0.79788456(x+0.044715x^3))) = x*t/(t+1), t=e^{2 inner}
__device__ __forceinline__ float gelu_fast(float v) {
    float x2 = v * v;
    float inner = v * fmaf(0.0356774081f, x2, 0.7978845608f);
    inner = fminf(fmaxf(inner, -20.f), 20.f);
    float t = exp2f(inner * 2.8853900817779268f); // 2*log2(e)
    return v * t * fast_rcp(t + 1.0f);
}

// ---------------- fused cast fp32 -> bf16 for x, enc + mask4 prep ----------------
// mask4[b][t][l16][nt] = maskp[b*2048 + t*64 + nt*16 + l16] ? -1e10 : 0  (8192 floats)
__global__ void cast2_bf16_k(const float* __restrict__ inA, unsigned short* __restrict__ outA,
                             const float* __restrict__ inB, unsigned short* __restrict__ outB,
                             int n4, const int* __restrict__ maskp, float* __restrict__ mask4) {
    if (blockIdx.y == 2) {
        int i = blockIdx.x * blockDim.x + threadIdx.x;
        if (i < 8192) {
            int nt = i & 3, l16 = (i >> 2) & 15, t = (i >> 6) & 31, b = (i >> 11) & 1;
            mask4[i] = maskp[b * 2048 + t * 64 + nt * 16 + l16] ? -1e10f : 0.0f;
        }
        return;
    }
    const float* in = blockIdx.y ? inB : inA;
    unsigned short* out = blockIdx.y ? outB : outA;
    int i = blockIdx.x * blockDim.x + threadIdx.x;
    if (i < n4) {
        float4 v = ((const float4*)in)[i];
        ushort4 o;
        o.x = f2bf(v.x); o.y = f2bf(v.y); o.z = f2bf(v.z); o.w = f2bf(v.w);
        ((ushort4*)out)[i] = o;
    }
}

// ---------------- fused weight transpose+cast: all 8 weights in one dispatch ----------------
__global__ void transpose_all_k(const float* __restrict__ s0, const float* __restrict__ s1,
                                const float* __restrict__ s2, const float* __restrict__ s3,
                                const float* __restrict__ s4, const float* __restrict__ s5,
                                const float* __restrict__ s6, const float* __restrict__ s7,
                                unsigned short* __restrict__ d0, unsigned short* __restrict__ d1,
                                unsigned short* __restrict__ d2, unsigned short* __restrict__ d3,
                                unsigned short* __restrict__ d4, unsigned short* __restrict__ d5,
                                unsigned short* __restrict__ d6, unsigned short* __restrict__ d7) {
    __shared__ float tile[32][33];
    int idx = blockIdx.x;
    const float* W; unsigned short* Wt; int K, N, bx, by;
    if (idx < 6144) {
        int which = idx >> 10, t = idx & 1023;
        bx = t & 31; by = t >> 5; K = 1024; N = 1024;
        switch (which) {
            case 0: W = s0; Wt = d0; break;
            case 1: W = s1; Wt = d1; break;
            case 2: W = s2; Wt = d2; break;
            case 3: W = s3; Wt = d3; break;
            case 4: W = s4; Wt = d4; break;
            default: W = s5; Wt = d5; break;
        }
    } else if (idx < 10240) {
        int t = idx - 6144;
        bx = t & 127; by = t >> 7; K = 1024; N = 4096;
        W = s6; Wt = d6;
    } else {
        int t = idx - 10240;
        bx = t & 31; by = t >> 5; K = 4096; N = 1024;
        W = s7; Wt = d7;
    }
    int k0 = by * 32, n0 = bx * 32;
    int tx = threadIdx.x, ty = threadIdx.y; // 32 x 8
#pragma unroll
    for (int i = 0; i < 32; i += 8)
        tile[ty + i][tx] = W[(long)(k0 + ty + i) * N + n0 + tx];
    __syncthreads();
#pragma unroll
    for (int i = 0; i < 32; i += 8)
        Wt[(long)(n0 + ty + i) * K + k0 + tx] = f2bf(tile[tx][ty + i]);
}

// ---------------- fused Q+K head split with XOR-8 group swizzle ----------------
__global__ __launch_bounds__(256) void split_qk_k(const unsigned short* __restrict__ inQ,
                                                  const unsigned short* __restrict__ inK,
                                                  int stride, int koff,
                                                  unsigned short* __restrict__ Qout,
                                                  unsigned short* __restrict__ Kout) {
    __shared__ __align__(16) unsigned short t[16][1024];
    long l0 = (long)blockIdx.x * 16;
    int tid = threadIdx.x;
    int h = tid >> 4, lr = tid & 15;
    long l = l0 + lr;
    int b = (int)(l >> 11);
    int ll = (int)(l & 2047);
    int sw = ll & 7;

    for (int c = tid; c < 2048; c += 256) {
        int r = c >> 7, col = (c & 127) * 8;
        *(uint4*)(&t[r][col]) = *(const uint4*)(inQ + (l0 + r) * stride + col);
    }
    __syncthreads();
    {
        unsigned short* op = Qout + ((long)(b * 16 + h) * 2048 + ll) * 64;
#pragma unroll
        for (int g = 0; g < 8; g++) {
            union { uint4 v; unsigned short s[8]; } u;
#pragma unroll
            for (int j = 0; j < 8; j++) u.s[j] = t[lr][(g * 8 + j) * 16 + h];
            *(uint4*)(op + (g ^ sw) * 8) = u.v;
        }
    }
    __syncthreads();
    for (int c = tid; c < 2048; c += 256) {
        int r = c >> 7, col = (c & 127) * 8;
        *(uint4*)(&t[r][col]) = *(const uint4*)(inK + (l0 + r) * stride + koff + col);
    }
    __syncthreads();
    {
        unsigned short* op = Kout + ((long)(b * 16 + h) * 2048 + ll) * 64;
#pragma unroll
        for (int g = 0; g < 8; g++) {
            union { uint4 v; unsigned short s[8]; } u;
#pragma unroll
            for (int j = 0; j < 8; j++) u.s[j] = t[lr][(g * 8 + j) * 16 + h];
            *(uint4*)(op + (g ^ sw) * 8) = u.v;
        }
    }
}

// ---------------- per-head transpose + m-perm, deswizzle-in / swizzle-out ----------------
__global__ __launch_bounds__(256) void transpose_heads_perm_k(const unsigned short* __restrict__ in,
                                                              unsigned short* __restrict__ out) {
    __shared__ unsigned short t[64][72];
    int bh = blockIdx.y;
    int m0 = blockIdx.x * 64;
    int tid = threadIdx.x;
    for (int c = tid; c < 512; c += 256) {
        int r = c >> 3, gp = c & 7;
        int glog = gp ^ (r & 7);
        uint4 v = *(const uint4*)(in + ((long)bh * 2048 + m0 + r) * 64 + gp * 8);
        *(uint4*)(&t[r][glog * 8]) = v;
    }
    __syncthreads();
    for (int c = tid; c < 512; c += 256) {
        int d = c >> 3, pb = (c & 7) * 8;
        union { uint4 v; unsigned short s[8]; } u;
#pragma unroll
        for (int j = 0; j < 8; j++) {
            int p = pb + j;
            int m = (p >> 2) + (p & 3) * 16;
            u.s[j] = t[m][d];
        }
        int gph = (pb >> 3) ^ (d & 7);
        *(uint4*)(out + ((long)bh * 64 + d) * 2048 + m0 + gph * 8) = u.v;
    }
}

// ---------------- GEMM v2: BK=64, XOR-swizzled staging, 2-way-free fragment reads ----------
// C(M,N) = A(M,K) @ Bt(N,K)^T, bf16 in, fp32 acc.
// EP: 0 = fp32 out, 2 = bias+gelu -> bf16, 3 = bias -> fp32, 4 = bf16, 6 = bias -> bf16
template <int EP, int BN>
__global__ __launch_bounds__(256) void gemm_k(const unsigned short* __restrict__ A,
                                              const unsigned short* __restrict__ Bt,
                                              void* __restrict__ outp,
                                              const float* __restrict__ bias,
                                              const unsigned short* __restrict__ A2,
                                              const unsigned short* __restrict__ Bt2,
                                              void* __restrict__ out2,
                                              int M, int N, int K) {
    if (blockIdx.z) { A = A2; Bt = Bt2; outp = out2; }
    __shared__ __align__(16) unsigned short As[128 * 64];
    __shared__ __align__(16) unsigned short Bs[BN * 64];
    const int NT = BN / 32;       // MFMA n-tiles per wave
    const int BG = BN / 32;       // B staging GLDS ops
    int tid = threadIdx.x;
    int wave = tid >> 6, lane = tid & 63;
    int wm = wave >> 1, wn = wave & 1;
    int quad = lane >> 4, l16 = lane & 15;
    int bm = blockIdx.y * 128, bn = blockIdx.x * BN;

    f32x4_t acc[4][NT] = {};

    // staging: thread t covers row i*32 + (t>>3); physical group (t&7) holds
    // logical k-group (t&7)^(row&7)  -> source col = ((t&7)^(row&7))*8
    int srow = tid >> 3;
    int sgrp = (tid & 7) ^ (srow & 7);
    const unsigned short* Ag[4];
#pragma unroll
    for (int i = 0; i < 4; i++)
        Ag[i] = A + (long)(bm + i * 32 + srow) * K + sgrp * 8;
    const unsigned short* Bg[BG];
#pragma unroll
    for (int i = 0; i < BG; i++)
        Bg[i] = Bt + (long)(bn + i * 32 + srow) * K + sgrp * 8;

    for (int k0 = 0; k0 < K; k0 += 64) {
        __syncthreads();
#pragma unroll
        for (int i = 0; i < 4; i++)
            __builtin_amdgcn_global_load_lds(GLB(Ag[i] + k0), LDS(As + i * 2048 + tid * 8), 16, 0, 0);
#pragma unroll
        for (int i = 0; i < BG; i++)
            __builtin_amdgcn_global_load_lds(GLB(Bg[i] + k0), LDS(Bs + i * 2048 + tid * 8), 16, 0, 0);
        __syncthreads();
#pragma unroll
        for (int kk = 0; kk < 2; kk++) {
            int xg = ((kk * 4 + quad) ^ (l16 & 7)) * 8;
            bf16x8_t af[4], bfr[NT];
#pragma unroll
            for (int t = 0; t < 4; t++)
                af[t] = *(const bf16x8_t*)(As + (wm * 64 + t * 16 + l16) * 64 + xg);
#pragma unroll
            for (int t = 0; t < NT; t++)
                bfr[t] = *(const bf16x8_t*)(Bs + (wn * (BN / 2) + t * 16 + l16) * 64 + xg);
#pragma unroll
            for (int mt = 0; mt < 4; mt++)
#pragma unroll
                for (int nt = 0; nt < NT; nt++)
                    acc[mt][nt] = __builtin_amdgcn_mfma_f32_16x16x32_bf16(af[mt], bfr[nt], acc[mt][nt], 0, 0, 0);
        }
    }

#pragma unroll
    for (int mt = 0; mt < 4; mt++)
#pragma unroll
        for (int nt = 0; nt < NT; nt++)
#pragma unroll
            for (int r = 0; r < 4; r++) {
                int gm = bm + wm * 64 + mt * 16 + quad * 4 + r;
                int gn = bn + wn * (BN / 2) + nt * 16 + l16;
                float v = acc[mt][nt][r];
                if (EP == 0) {
                    ((float*)outp)[(long)gm * N + gn] = v;
                } else if (EP == 2) {
                    v = gelu_fast(v + bias[gn]);
                    ((unsigned short*)outp)[(long)gm * N + gn] = f2bf(v);
                } else if (EP == 3) {
                    ((float*)outp)[(long)gm * N + gn] = v + bias[gn];
                } else if (EP == 6) {
                    ((unsigned short*)outp)[(long)gm * N + gn] = f2bf(v + bias[gn]);
                } else {
                    ((unsigned short*)outp)[(long)gm * N + gn] = f2bf(v);
                }
            }
}

// ---------------- flash attention v7 (measured 90.5us): 24576B LDS ----------------
// Qh, Kh: [bh][2048][64] swizzled; KhTp: [bh][64][2048] perm+swizzled.
// mask4: [b][t][l16][nt] floats (0 or -1e10). out: [4096][1024] bf16 (col=d*16+h).
template <int USE_MASK>
__global__ __launch_bounds__(256, 4) void flash_attn7_k(const unsigned short* __restrict__ Qh,
                                                        const unsigned short* __restrict__ Kh,
                                                        const unsigned short* __restrict__ KhTp,
                                                        const float* __restrict__ mask4,
                                                        unsigned short* __restrict__ out) {
    __shared__ __align__(16) unsigned short K1[64 * 64]; // [m][d] swizzled groups
    __shared__ __align__(16) unsigned short K2[64 * 64]; // [d][p] swizzled groups
    __shared__ __align__(16) unsigned short Ps[64 * 64]; // [l][p] XOR-8 row-swizzled

    int tid = threadIdx.x;
    int wave = tid >> 6, lane = tid & 63;
    int quad = lane >> 4, l16 = lane & 15;
    int bh = blockIdx.y, b = bh >> 4, h = bh & 15;
    int l0 = blockIdx.x * 64;
    const unsigned short* k1p = Kh + (long)bh * 2048 * 64 + tid * 8;
    const unsigned short* k2p = KhTp + (long)bh * 64 * 2048 + (long)(tid >> 3) * 2048 + (tid & 7) * 8;
    const float* m4p = mask4 + b * 2048 + l16 * 4;

    int sw = l16 & 7;

    // Q fragments live in registers for the whole kernel (wave-invariant rows)
    const unsigned short* qrow = Qh + ((long)bh * 2048 + l0 + wave * 16 + l16) * 64;
    bf16x8_t qf[2];
#pragma unroll
    for (int kk = 0; kk < 2; kk++)
        qf[kk] = *(const bf16x8_t*)(qrow + ((kk * 4 + quad) ^ sw) * 8);

    const float C1 = 0.125f * LOG2E;
    f32x4_t acc_o[4] = {};
    float rs[4] = {0.f, 0.f, 0.f, 0.f};

    for (int t = 0; t < 32; ++t) {
        __syncthreads();   // all waves done reading previous tile
        __builtin_amdgcn_global_load_lds(GLB(k1p), LDS(K1 + tid * 8), 16, 0, 0);
        __builtin_amdgcn_global_load_lds(GLB(k1p + 2048), LDS(K1 + tid * 8 + 2048), 16, 0, 0);
        __builtin_amdgcn_global_load_lds(GLB(k2p), LDS(K2 + tid * 8), 16, 0, 0);
        __builtin_amdgcn_global_load_lds(GLB(k2p + 32 * 2048), LDS(K2 + tid * 8 + 2048), 16, 0, 0);
        float4 mq = make_float4(0.f, 0.f, 0.f, 0.f);
        if (USE_MASK) mq = *(const float4*)(m4p + t * 64);
        __syncthreads();   // staging complete

        // S = Q @ Ktile^T : wave handles 16 Q rows (band = wave*16), 64 m cols
        f32x4_t sacc[4] = {};
#pragma unroll
        for (int kk = 0; kk < 2; kk++) {
            int xg = ((kk * 4 + quad) ^ sw) * 8;
#pragma unroll
            for (int nt = 0; nt < 4; nt++) {
                bf16x8_t bfr = *(const bf16x8_t*)(K1 + (nt * 16 + l16) * 64 + xg);
                sacc[nt] = __builtin_amdgcn_mfma_f32_16x16x32_bf16(qf[kk], bfr, sacc[nt], 0, 0, 0);
            }
        }

        // p = exp2(s*C1 + mf); per-lane row-sum; write P 8B (4 bf16, permuted cols, swizzled)
#pragma unroll
        for (int r = 0; r < 4; r++) {
            float p0 = exp2f(fmaf(sacc[0][r], C1, mq.x));
            float p1 = exp2f(fmaf(sacc[1][r], C1, mq.y));
            float p2 = exp2f(fmaf(sacc[2][r], C1, mq.z));
            float p3 = exp2f(fmaf(sacc[3][r], C1, mq.w));
            rs[r] += (p0 + p1) + (p2 + p3);
            uint2 pk; pk.x = pack2bf(p0, p1); pk.y = pack2bf(p2, p3);
            int Rrow = wave * 16 + quad * 4 + r;
            int grp = (l16 >> 1) ^ (Rrow & 7);
            *(uint2*)(Ps + Rrow * 64 + grp * 8 + (l16 & 1) * 4) = pk;
        }

        // O += P @ Ktile : A = own band of Ps (swizzled), B = K2 (swizzled)
#pragma unroll
        for (int kk = 0; kk < 2; kk++) {
            int xg = ((kk * 4 + quad) ^ sw) * 8;
            int Rr = wave * 16 + l16;
            int pg = ((kk * 4 + quad) ^ (l16 & 7)) * 8;
            bf16x8_t af = *(const bf16x8_t*)(Ps + Rr * 64 + pg);
#pragma unroll
            for (int nt = 0; nt < 4; nt++) {
                bf16x8_t bfr = *(const bf16x8_t*)(K2 + (nt * 16 + l16) * 64 + xg);
                acc_o[nt] = __builtin_amdgcn_mfma_f32_16x16x32_bf16(af, bfr, acc_o[nt], 0, 0, 0);
            }
        }
        k1p += 4096;
        k2p += 64;
    }

    // single final reduction of row sums across the 16 l16 lanes
#pragma unroll
    for (int r = 0; r < 4; r++) {
#pragma unroll
        for (int d = 1; d < 16; d <<= 1) rs[r] += __shfl_xor(rs[r], d);
    }

#pragma unroll
    for (int r = 0; r < 4; r++) {
        float inv = 1.0f / rs[r];
        int l = l0 + wave * 16 + quad * 4 + r;
#pragma unroll
        for (int nt = 0; nt < 4; nt++) {
            int d = nt * 16 + l16;
            out[((long)(b * 2048 + l)) * 1024 + d * 16 + h] = f2bf(acc_o[nt][r] * inv);
        }
    }
}

// ---------------- residual + layernorm ----------------
// AIN_BF16: residual-stream input dtype. OUT_F32: write fp32 (final) else bf16.
template <int AIN_BF16, int OUT_F32>
__global__ __launch_bounds__(256) void resid_ln_k(const void* __restrict__ ap,
                                                  const unsigned short* __restrict__ rb,
                                                  const float* __restrict__ g,
                                                  const float* __restrict__ bb,
                                                  float* __restrict__ outf,
                                                  unsigned short* __restrict__ outb) {
    long row = blockIdx.x;
    int tid = threadIdx.x;
    float x0, x1, x2, x3;
    if (AIN_BF16) {
        ushort4 va = ((const ushort4*)((const unsigned short*)ap + row * 1024))[tid];
        x0 = bf2f(va.x); x1 = bf2f(va.y); x2 = bf2f(va.z); x3 = bf2f(va.w);
    } else {
        float4 va = ((const float4*)((const float*)ap + row * 1024))[tid];
        x0 = va.x; x1 = va.y; x2 = va.z; x3 = va.w;
    }
    ushort4 vr = ((const ushort4*)(rb + row * 1024))[tid];
    x0 += bf2f(vr.x); x1 += bf2f(vr.y); x2 += bf2f(vr.z); x3 += bf2f(vr.w);
    float s = x0 + x1 + x2 + x3;
    float sq = x0 * x0 + x1 * x1 + x2 * x2 + x3 * x3;
#pragma unroll
    for (int d = 1; d < 64; d <<= 1) { s += __shfl_xor(s, d); sq += __shfl_xor(sq, d); }
    __shared__ float ss[4], ssq[4];
    int wave = tid >> 6, lane = tid & 63;
    if (lane == 0) { ss[wave] = s; ssq[wave] = sq; }
    __syncthreads();
    s = ss[0] + ss[1] + ss[2] + ss[3];
    sq = ssq[0] + ssq[1] + ssq[2] + ssq[3];
    float mean = s * (1.0f / 1024.0f);
    float var = sq * (1.0f / 1024.0f) - mean * mean;
    float rstd = rsqrtf(var + 1e-5f);
    float4 vg = ((const float4*)g)[tid];
    float4 vb = ((const float4*)bb)[tid];
    float y0 = (x0 - mean) * rstd * vg.x + vb.x;
    float y1 = (x1 - mean) * rstd * vg.y + vb.y;
    float y2 = (x2 - mean) * rstd * vg.z + vb.z;
    float y3 = (x3 - mean) * rstd * vg.w + vb.w;
    if (OUT_F32) {
        float4 o; o.x = y0; o.y = y1; o.z = y2; o.w = y3;
        ((float4*)(outf + row * 1024))[tid] = o;
    } else {
        ushort4 ob; ob.x = f2bf(y0); ob.y = f2bf(y1); ob.z = f2bf(y2); ob.w = f2bf(y3);
        ((ushort4*)(outb + row * 1024))[tid] = ob;
    }
}

extern "C" void kernel_launch(void* const* d_in, const int* in_sizes, int n_in,
                              void* d_out, int out_size, void* d_ws, size_t ws_size,
                              hipStream_t stream) {
    const float* x    = (const float*)d_in[0];
    const float* enc  = (const float*)d_in[1];
    const int*   mask = (const int*)d_in[2];
    const float* q1W  = (const float*)d_in[3];
    const float* w1W  = (const float*)d_in[4];
    const float* o1W  = (const float*)d_in[5];
    const float* q2W  = (const float*)d_in[6];
    const float* w2W  = (const float*)d_in[7];
    const float* o2W  = (const float*)d_in[8];
    const float* ffW1 = (const float*)d_in[9];
    const float* ffb1 = (const float*)d_in[10];
    const float* ffW2 = (const float*)d_in[11];
    const float* ffb2 = (const float*)d_in[12];
    const float* g1 = (const float*)d_in[13];
    const float* b1 = (const float*)d_in[14];
    const float* g2 = (const float*)d_in[15];
    const float* b2 = (const float*)d_in[16];
    const float* g3 = (const float*)d_in[17];
    const float* b3 = (const float*)d_in[18];
    float* outp = (float*)d_out;

    const int T = 4096;   // B*L
    const int D = 1024;
    const int F = 4096;   // MLP

    char* ws = (char*)d_ws;
    auto alloc = [&](size_t sz) { char* p = ws; ws += (sz + 255) & ~(size_t)255; return p; };
    unsigned short* qw1Wt = (unsigned short*)alloc((size_t)2 * D * D * 2); // fused [2048][1024]
    unsigned short* o1Wt  = (unsigned short*)alloc((size_t)D * D * 2);
    unsigned short* q2Wt  = (unsigned short*)alloc((size_t)D * D * 2);
    unsigned short* w2Wt  = (unsigned short*)alloc((size_t)D * D * 2);
    unsigned short* o2Wt  = (unsigned short*)alloc((size_t)D * D * 2);
    unsigned short* ffW1t = (unsigned short*)alloc((size_t)F * D * 2);
    unsigned short* ffW2t = (unsigned short*)alloc((size_t)D * F * 2);
    unsigned short* xb    = (unsigned short*)alloc((size_t)T * D * 2);
    unsigned short* encb  = (unsigned short*)alloc((size_t)T * D * 2);
    unsigned short* Qhb   = (unsigned short*)alloc((size_t)T * D * 2);
    unsigned short* Khb   = (unsigned short*)alloc((size_t)T * D * 2);
    unsigned short* KhTb  = (unsigned short*)alloc((size_t)T * D * 2);
    unsigned short* attnb = (unsigned short*)alloc((size_t)T * D * 2);
    float*          mask4b= (float*)alloc((size_t)8192 * 4);
    unsigned short* projb = (unsigned short*)alloc((size_t)T * D * 2);
    unsigned short* x1s   = (unsigned short*)alloc((size_t)T * D * 2);
    unsigned short* x2s   = (unsigned short*)alloc((size_t)T * D * 2);
    unsigned short* S1    = (unsigned short*)alloc((size_t)T * F * 2); // 32 MB scratch
    unsigned short* tmpqw = S1;                 // [4096][2048]
    unsigned short* q2o   = S1;                 // [4096][1024]
    unsigned short* w2o   = S1 + (size_t)T * D; // [4096][1024]
    unsigned short* hb    = S1;                 // [4096][4096]

    dim3 blk256(256);
    dim3 tblk(32, 8);

    // prologue: fused casts (+ mask4 prep) + fused weight transposes
    cast2_bf16_k<<<dim3(T * D / 4 / 256, 3), blk256, 0, stream>>>(x, xb, enc, encb, T * D / 4, mask, mask4b);
    transpose_all_k<<<dim3(14336), tblk, 0, stream>>>(
        q1W, w1W, o1W, q2W, w2W, o2W, ffW1, ffW2,
        qw1Wt, qw1Wt + (size_t)D * D, o1Wt, q2Wt, w2Wt, o2Wt, ffW1t, ffW2t);

    // ---- self attention ----
    gemm_k<4, 64><<<dim3(2 * D / 64, T / 128, 1), blk256, 0, stream>>>(
        xb, qw1Wt, tmpqw, nullptr, nullptr, nullptr, nullptr, T, 2 * D, D);
    split_qk_k<<<dim3(T / 16), blk256, 0, stream>>>(tmpqw, tmpqw, 2 * D, D, Qhb, Khb);
    transpose_heads_perm_k<<<dim3(32, 32), blk256, 0, stream>>>(Khb, KhTb);
    flash_attn7_k<0><<<dim3(32, 32), blk256, 0, stream>>>(Qhb, Khb, KhTb, nullptr, attnb);
    gemm_k<4, 64><<<dim3(D / 64, T / 128, 1), blk256, 0, stream>>>(
        attnb, o1Wt, projb, nullptr, nullptr, nullptr, nullptr, T, D, D);
    resid_ln_k<0, 0><<<dim3(T), blk256, 0, stream>>>(x, projb, g1, b1, nullptr, x1s);

    // ---- cross attention ----
    gemm_k<4, 64><<<dim3(D / 64, T / 128, 2), blk256, 0, stream>>>(
        x1s, q2Wt, q2o, nullptr, encb, w2Wt, w2o, T, D, D);
    split_qk_k<<<dim3(T / 16), blk256, 0, stream>>>(q2o, w2o, D, 0, Qhb, Khb);
    transpose_heads_perm_k<<<dim3(32, 32), blk256, 0, stream>>>(Khb, KhTb);
    flash_attn7_k<1><<<dim3(32, 32), blk256, 0, stream>>>(Qhb, Khb, KhTb, mask4b, attnb);
    gemm_k<4, 64><<<dim3(D / 64, T / 128, 1), blk256, 0, stream>>>(
        attnb, o2Wt, projb, nullptr, nullptr, nullptr, nullptr, T, D, D);
    resid_ln_k<1, 0><<<dim3(T), blk256, 0, stream>>>(x1s, projb, g2, b2, nullptr, x2s);

    // ---- feed forward ----
    gemm_k<2, 128><<<dim3(F / 128, T / 128, 1), blk256, 0, stream>>>(
        x2s, ffW1t, hb, ffb1, nullptr, nullptr, nullptr, T, F, D);
    gemm_k<6, 64><<<dim3(D / 64, T / 128, 1), blk256, 0, stream>>>(
        hb, ffW2t, projb, ffb2, nullptr, nullptr, nullptr, T, D, F);
    resid_ln_k<1, 1><<<dim3(T), blk256, 0, stream>>>(x2s, projb, g3, b3, outp, nullptr);
}